// Round 2
// baseline (864.402 us; speedup 1.0000x reference)
//
#include <hip/hip_runtime.h>
#include <hip/hip_bf16.h>

typedef unsigned short u16;
typedef short bf16x8 __attribute__((ext_vector_type(8)));
typedef float f32x4 __attribute__((ext_vector_type(4)));

__device__ __forceinline__ float b2f(u16 u) {
  union { float f; unsigned int i; } v; v.i = ((unsigned int)u) << 16; return v.f;
}
__device__ __forceinline__ u16 f2b(float f) {
  union { float f; unsigned int i; } v; v.f = f;
  unsigned int r = v.i + 0x7fffu + ((v.i >> 16) & 1u);
  return (u16)(r >> 16);
}
__device__ __forceinline__ u16 to_b(float v) { return f2b(v); }
__device__ __forceinline__ u16 to_b(u16 v) { return v; }
__device__ __forceinline__ float to_f(float v) { return v; }
__device__ __forceinline__ float to_f(u16 v) { return b2f(v); }

// C[M,N] = A[M,K] * Bt[N,K]^T  (+bias[N]) (*scale) (optional ReLU).
// A is fp32 (AF32=true) or bf16; Bt/C bf16; fp32 accumulate.
// Requires M%128==0, N%128==0, K%32==0.
template <bool RELU, bool AF32>
__global__ __launch_bounds__(256)
void gemm_nt(const void* __restrict__ Av, const u16* __restrict__ Bt,
             const float* __restrict__ bias, u16* __restrict__ C,
             int M, int N, int K, float scale) {
  __shared__ __align__(16) u16 As[128][40];  // 32 + 8 pad
  __shared__ __align__(16) u16 Bs[128][40];
  const int m0 = blockIdx.y * 128;
  const int n0 = blockIdx.x * 128;
  const int t = threadIdx.x;
  const int w = t >> 6, lane = t & 63;
  const int wm = (w >> 1) * 64, wn = (w & 1) * 64;
  const int lr = lane & 15, q = lane >> 4;

  f32x4 acc[4][4];
#pragma unroll
  for (int i = 0; i < 4; i++)
#pragma unroll
    for (int j = 0; j < 4; j++) acc[i][j] = (f32x4){0.f, 0.f, 0.f, 0.f};

  for (int k0 = 0; k0 < K; k0 += 32) {
#pragma unroll
    for (int i = 0; i < 2; ++i) {
      int idx = t + i * 256;       // 0..511
      int row = idx >> 2;          // 0..127
      int col = (idx & 3) * 8;     // 0,8,16,24
      if (AF32) {
        const float* ap = (const float*)Av + (size_t)(m0 + row) * K + k0 + col;
        float4 a0 = *(const float4*)ap;
        float4 a1 = *(const float4*)(ap + 4);
        u16 tmp[8] = {f2b(a0.x), f2b(a0.y), f2b(a0.z), f2b(a0.w),
                      f2b(a1.x), f2b(a1.y), f2b(a1.z), f2b(a1.w)};
        *(uint4*)&As[row][col] = *(uint4*)tmp;
      } else {
        *(uint4*)&As[row][col] =
            *(const uint4*)((const u16*)Av + (size_t)(m0 + row) * K + k0 + col);
      }
      *(uint4*)&Bs[row][col] = *(const uint4*)(Bt + (size_t)(n0 + row) * K + k0 + col);
    }
    __syncthreads();
    bf16x8 af[4], bf[4];
#pragma unroll
    for (int i = 0; i < 4; i++) af[i] = *(const bf16x8*)&As[wm + i * 16 + lr][q * 8];
#pragma unroll
    for (int j = 0; j < 4; j++) bf[j] = *(const bf16x8*)&Bs[wn + j * 16 + lr][q * 8];
#pragma unroll
    for (int i = 0; i < 4; i++)
#pragma unroll
      for (int j = 0; j < 4; j++)
        acc[i][j] = __builtin_amdgcn_mfma_f32_16x16x32_bf16(af[i], bf[j], acc[i][j], 0, 0, 0);
    __syncthreads();
  }

#pragma unroll
  for (int j = 0; j < 4; j++) {
    int cg = n0 + wn + j * 16 + lr;           // D col = lane&15
    float bb = bias ? bias[cg] : 0.0f;
#pragma unroll
    for (int i = 0; i < 4; i++) {
      int rbase = m0 + wm + i * 16 + q * 4;   // D row = quad*4 + reg
#pragma unroll
      for (int r = 0; r < 4; r++) {
        float vv = acc[i][j][r] * scale + bb;
        if (RELU) vv = fmaxf(vv, 0.0f);
        C[(size_t)(rbase + r) * N + cg] = f2b(vv);
      }
    }
  }
}

// dst[C,R] = to_bf16(src[R,C])^T, batched via blockIdx.z. R%32==0, C%32==0.
template <typename TS>
__global__ __launch_bounds__(1024)
void transpose_b(const TS* __restrict__ src, u16* __restrict__ dst, int R, int Cc) {
  __shared__ u16 tile[32][33];
  size_t bo = (size_t)blockIdx.z * R * Cc;
  int r = blockIdx.y * 32 + threadIdx.y;
  int c = blockIdx.x * 32 + threadIdx.x;
  tile[threadIdx.y][threadIdx.x] = to_b(src[bo + (size_t)r * Cc + c]);
  __syncthreads();
  int rr = blockIdx.x * 32 + threadIdx.y;
  int cc = blockIdx.y * 32 + threadIdx.x;
  dst[bo + (size_t)rr * R + cc] = tile[threadIdx.x][threadIdx.y];
}

// In-place row softmax over 4096 bf16 logits; one block per row.
__global__ __launch_bounds__(256)
void softmax_inplace(u16* __restrict__ S) {
  const int row = blockIdx.x;
  u16* p = S + (size_t)row * 4096;
  const int t = threadIdx.x;
  float v[16];
  float mx = -1e30f;
#pragma unroll
  for (int i = 0; i < 16; i++) { v[i] = b2f(p[t + i * 256]); mx = fmaxf(mx, v[i]); }
#pragma unroll
  for (int o = 32; o > 0; o >>= 1) mx = fmaxf(mx, __shfl_xor(mx, o));
  __shared__ float red[4];
  int w = t >> 6;
  if ((t & 63) == 0) red[w] = mx;
  __syncthreads();
  mx = fmaxf(fmaxf(red[0], red[1]), fmaxf(red[2], red[3]));
  __syncthreads();
  float s = 0.f;
#pragma unroll
  for (int i = 0; i < 16; i++) { v[i] = __expf(v[i] - mx); s += v[i]; }
#pragma unroll
  for (int o = 32; o > 0; o >>= 1) s += __shfl_xor(s, o);
  if ((t & 63) == 0) red[w] = s;
  __syncthreads();
  s = red[0] + red[1] + red[2] + red[3];
  float inv = 1.0f / s;
#pragma unroll
  for (int i = 0; i < 16; i++) p[t + i * 256] = f2b(v[i] * inv);
}

// O[row] = LayerNorm(X[row] + R[row]; g, b). Row length 512. 1 row/wave, 4 waves/block.
template <typename TX, typename TO>
__global__ __launch_bounds__(256)
void add_ln(const TX* __restrict__ X, const u16* __restrict__ Rr,
            const float* __restrict__ g, const float* __restrict__ b,
            TO* __restrict__ O) {
  const int row = blockIdx.x * 4 + (threadIdx.x >> 6);
  const int lane = threadIdx.x & 63;
  const size_t base = (size_t)row * 512 + lane * 8;
  float z[8];
  float s1 = 0.f, s2 = 0.f;
#pragma unroll
  for (int i = 0; i < 8; i++) {
    z[i] = to_f(X[base + i]) + b2f(Rr[base + i]);
    s1 += z[i]; s2 += z[i] * z[i];
  }
#pragma unroll
  for (int o = 32; o > 0; o >>= 1) { s1 += __shfl_xor(s1, o); s2 += __shfl_xor(s2, o); }
  const float mu = s1 * (1.0f / 512.0f);
  const float var = s2 * (1.0f / 512.0f) - mu * mu;
  const float rstd = rsqrtf(var + 1e-5f);
#pragma unroll
  for (int i = 0; i < 8; i++) {
    int c = lane * 8 + i;
    float vv = (z[i] - mu) * rstd * g[c] + b[c];
    O[base + i] = (TO)0 == (TO)0 ? (TO)0 : (TO)0;  // placeholder avoided below
  }
  // (rewritten store loop to keep types exact)
#pragma unroll
  for (int i = 0; i < 8; i++) {
    int c = lane * 8 + i;
    float vv = (z[i] - mu) * rstd * g[c] + b[c];
    if (sizeof(TO) == 2) ((u16*)O)[base + i] = f2b(vv);
    else ((float*)O)[base + i] = vv;
  }
}

extern "C" void kernel_launch(void* const* d_in, const int* in_sizes, int n_in,
                              void* d_out, int out_size, void* d_ws, size_t ws_size,
                              hipStream_t stream) {
  const float* x   = (const float*)d_in[0];
  const float* Wq  = (const float*)d_in[1];
  const float* bq  = (const float*)d_in[2];
  const float* Wk  = (const float*)d_in[3];
  const float* bk  = (const float*)d_in[4];
  const float* Wv  = (const float*)d_in[5];
  const float* bv  = (const float*)d_in[6];
  const float* g1  = (const float*)d_in[7];
  const float* b1  = (const float*)d_in[8];
  const float* g2  = (const float*)d_in[9];
  const float* b2  = (const float*)d_in[10];
  const float* W1  = (const float*)d_in[11];
  const float* bf1 = (const float*)d_in[12];
  const float* W2  = (const float*)d_in[13];
  const float* bf2 = (const float*)d_in[14];
  float* out = (float*)d_out;

  char* ws = (char*)d_ws;
  const size_t U = 16777216;  // 16384*512*2 bytes
  u16* Qb  = (u16*)(ws + 0 * U);
  u16* Kb  = (u16*)(ws + 1 * U);
  u16* Vb  = (u16*)(ws + 2 * U);
  u16* Vt  = (u16*)(ws + 3 * U);
  u16* att = (u16*)(ws + 4 * U);
  u16* x1  = (u16*)(ws + 5 * U);
  u16* sc  = (u16*)(ws + 6 * U);   // 32 MB scores (per-batch, reused)
  u16* h   = (u16*)(ws + 6 * U);   // 64 MB h, after attention is done
  u16* ffn = (u16*)(ws + 10 * U);
  u16* wqt = (u16*)(ws + 11 * U);
  u16* wkt = wqt + 512 * 512;
  u16* wvt = wkt + 512 * 512;
  u16* w1t = wvt + 512 * 512;          // [2048,512]
  u16* w2t = w1t + 512 * 2048;         // [512,2048]

  dim3 tb(32, 32);
  // Pre-transpose weights (fp32 -> bf16) to NT form
  transpose_b<float><<<dim3(16, 16, 1), tb, 0, stream>>>(Wq, wqt, 512, 512);
  transpose_b<float><<<dim3(16, 16, 1), tb, 0, stream>>>(Wk, wkt, 512, 512);
  transpose_b<float><<<dim3(16, 16, 1), tb, 0, stream>>>(Wv, wvt, 512, 512);
  transpose_b<float><<<dim3(64, 16, 1), tb, 0, stream>>>(W1, w1t, 512, 2048);
  transpose_b<float><<<dim3(16, 64, 1), tb, 0, stream>>>(W2, w2t, 2048, 512);

  // QKV projections: [16384,512] x [512,512], A is fp32 x
  gemm_nt<false, true><<<dim3(4, 128), 256, 0, stream>>>(x, wqt, bq, Qb, 16384, 512, 512, 1.0f);
  gemm_nt<false, true><<<dim3(4, 128), 256, 0, stream>>>(x, wkt, bk, Kb, 16384, 512, 512, 1.0f);
  gemm_nt<false, true><<<dim3(4, 128), 256, 0, stream>>>(x, wvt, bv, Vb, 16384, 512, 512, 1.0f);

  // V^T per batch for the PV GEMM (bf16 -> bf16)
  transpose_b<u16><<<dim3(16, 128, 4), tb, 0, stream>>>(Vb, Vt, 4096, 512);

  const float scl = 0.044194173824159216f;  // 1/sqrt(512)
  for (int b = 0; b < 4; b++) {
    const u16* Qp  = Qb + (size_t)b * 4096 * 512;
    const u16* Kp  = Kb + (size_t)b * 4096 * 512;
    const u16* Vtp = Vt + (size_t)b * 4096 * 512;
    u16* attp = att + (size_t)b * 4096 * 512;
    // scores = scale * Q K^T
    gemm_nt<false, false><<<dim3(32, 32), 256, 0, stream>>>(Qp, Kp, nullptr, sc, 4096, 4096, 512, scl);
    softmax_inplace<<<4096, 256, 0, stream>>>(sc);
    // att = P V : Bt = V^T [512,4096]
    gemm_nt<false, false><<<dim3(4, 32), 256, 0, stream>>>(sc, Vtp, nullptr, attp, 4096, 512, 4096, 1.0f);
  }

  // x1 = LN(x + att)   (x fp32, att bf16, x1 bf16)
  add_ln<float, u16><<<4096, 256, 0, stream>>>(x, att, g1, b1, x1);
  // h = relu(x1 W1 + bf1): [16384,2048]
  gemm_nt<true, false><<<dim3(16, 128), 256, 0, stream>>>(x1, w1t, bf1, h, 16384, 2048, 512, 1.0f);
  // ffn = h W2 + bf2: [16384,512]
  gemm_nt<false, false><<<dim3(4, 128), 256, 0, stream>>>(h, w2t, bf2, ffn, 16384, 512, 2048, 1.0f);
  // out = LN(x1 + ffn) -> fp32
  add_ln<u16, float><<<4096, 256, 0, stream>>>(x1, ffn, g2, b2, out);
}

// Round 3
// 766.358 us; speedup vs baseline: 1.1279x; 1.1279x over previous
//
#include <hip/hip_runtime.h>
#include <hip/hip_bf16.h>

typedef unsigned short u16;
typedef short bf16x8 __attribute__((ext_vector_type(8)));
typedef float f32x4 __attribute__((ext_vector_type(4)));

__device__ __forceinline__ float b2f(u16 u) {
  union { float f; unsigned int i; } v; v.i = ((unsigned int)u) << 16; return v.f;
}
__device__ __forceinline__ u16 f2b(float f) {
  union { float f; unsigned int i; } v; v.f = f;
  unsigned int r = v.i + 0x7fffu + ((v.i >> 16) & 1u);
  return (u16)(r >> 16);
}
__device__ __forceinline__ u16 to_b(float v) { return f2b(v); }
__device__ __forceinline__ u16 to_b(u16 v) { return v; }
__device__ __forceinline__ float to_f(float v) { return v; }
__device__ __forceinline__ float to_f(u16 v) { return b2f(v); }

// C[M,N] = A[M,K] * Bt[N,K]^T (+bias[N]) (*scale) (ReLU opt).
// A fp32 or bf16 (AF32). C: bf16 store, or fp32 atomicAdd (ATOMIC, for split-K; bias must be null).
// blockIdx.z = batch*nsplit + split. All tile dims: M%128==0, N%128==0, (K/nsplit)%32==0.
template <bool RELU, bool AF32, bool ATOMIC>
__global__ __launch_bounds__(256)
void gemm_nt(const void* __restrict__ Av, const u16* __restrict__ Bt,
             const float* __restrict__ bias, void* __restrict__ Cv,
             int N, int K, int nsplit,
             int lda, int ldb, int ldc,
             long sA, long sB, long sC, float scale) {
  __shared__ __align__(16) u16 As[128][40];  // 32 + 8 pad
  __shared__ __align__(16) u16 Bs[128][40];
  const int z = blockIdx.z;
  const int batch = z / nsplit, split = z % nsplit;
  const int Ks = K / nsplit;
  const long aoff = (long)batch * sA + (long)split * Ks;
  const long boff = (long)batch * sB + (long)split * Ks;
  const long coff = (long)batch * sC;
  const int m0 = blockIdx.y * 128;
  const int n0 = blockIdx.x * 128;
  const int t = threadIdx.x;
  const int w = t >> 6, lane = t & 63;
  const int wm = (w >> 1) * 64, wn = (w & 1) * 64;
  const int lr = lane & 15, q = lane >> 4;

  f32x4 acc[4][4];
#pragma unroll
  for (int i = 0; i < 4; i++)
#pragma unroll
    for (int j = 0; j < 4; j++) acc[i][j] = (f32x4){0.f, 0.f, 0.f, 0.f};

  for (int k0 = 0; k0 < Ks; k0 += 32) {
#pragma unroll
    for (int i = 0; i < 2; ++i) {
      int idx = t + i * 256;       // 0..511
      int row = idx >> 2;          // 0..127
      int col = (idx & 3) * 8;     // 0,8,16,24
      if (AF32) {
        const float* ap = (const float*)Av + aoff + (long)(m0 + row) * lda + k0 + col;
        float4 a0 = *(const float4*)ap;
        float4 a1 = *(const float4*)(ap + 4);
        u16 tmp[8] = {f2b(a0.x), f2b(a0.y), f2b(a0.z), f2b(a0.w),
                      f2b(a1.x), f2b(a1.y), f2b(a1.z), f2b(a1.w)};
        *(uint4*)&As[row][col] = *(uint4*)tmp;
      } else {
        *(uint4*)&As[row][col] =
            *(const uint4*)((const u16*)Av + aoff + (long)(m0 + row) * lda + k0 + col);
      }
      *(uint4*)&Bs[row][col] =
          *(const uint4*)(Bt + boff + (long)(n0 + row) * ldb + k0 + col);
    }
    __syncthreads();
    bf16x8 af[4], bf[4];
#pragma unroll
    for (int i = 0; i < 4; i++) af[i] = *(const bf16x8*)&As[wm + i * 16 + lr][q * 8];
#pragma unroll
    for (int j = 0; j < 4; j++) bf[j] = *(const bf16x8*)&Bs[wn + j * 16 + lr][q * 8];
#pragma unroll
    for (int i = 0; i < 4; i++)
#pragma unroll
      for (int j = 0; j < 4; j++)
        acc[i][j] = __builtin_amdgcn_mfma_f32_16x16x32_bf16(af[i], bf[j], acc[i][j], 0, 0, 0);
    __syncthreads();
  }

#pragma unroll
  for (int j = 0; j < 4; j++) {
    int cg = n0 + wn + j * 16 + lr;           // D col = lane&15
    float bb = (!ATOMIC && bias) ? bias[cg] : 0.0f;
#pragma unroll
    for (int i = 0; i < 4; i++) {
      int rbase = m0 + wm + i * 16 + q * 4;   // D row = quad*4 + reg
#pragma unroll
      for (int r = 0; r < 4; r++) {
        float vv = acc[i][j][r] * scale;
        if (ATOMIC) {
          atomicAdd((float*)Cv + coff + (long)(rbase + r) * ldc + cg, vv);
        } else {
          vv += bb;
          if (RELU) vv = fmaxf(vv, 0.0f);
          ((u16*)Cv)[coff + (long)(rbase + r) * ldc + cg] = f2b(vv);
        }
      }
    }
  }
}

// dst[z*dbs + c*R + r] = to_bf16(src[z*sbs + r*src_ld + c]). R%32==0, C%32==0.
template <typename TS>
__global__ __launch_bounds__(1024)
void transpose_b(const TS* __restrict__ src, u16* __restrict__ dst,
                 int R, int Cc, int src_ld, long sbs, long dbs) {
  __shared__ u16 tile[32][33];
  int r = blockIdx.y * 32 + threadIdx.y;
  int c = blockIdx.x * 32 + threadIdx.x;
  tile[threadIdx.y][threadIdx.x] = to_b(src[(long)blockIdx.z * sbs + (long)r * src_ld + c]);
  __syncthreads();
  int rr = blockIdx.x * 32 + threadIdx.y;
  int cc = blockIdx.y * 32 + threadIdx.x;
  dst[(long)blockIdx.z * dbs + (long)rr * R + cc] = tile[threadIdx.x][threadIdx.y];
}

// In-place row softmax over 4096 bf16 logits; one block per row.
__global__ __launch_bounds__(256)
void softmax_inplace(u16* __restrict__ S) {
  const int row = blockIdx.x;
  u16* p = S + (size_t)row * 4096;
  const int t = threadIdx.x;
  float v[16];
  float mx = -1e30f;
#pragma unroll
  for (int i = 0; i < 16; i++) { v[i] = b2f(p[t + i * 256]); mx = fmaxf(mx, v[i]); }
#pragma unroll
  for (int o = 32; o > 0; o >>= 1) mx = fmaxf(mx, __shfl_xor(mx, o));
  __shared__ float red[4];
  int w = t >> 6;
  if ((t & 63) == 0) red[w] = mx;
  __syncthreads();
  mx = fmaxf(fmaxf(red[0], red[1]), fmaxf(red[2], red[3]));
  __syncthreads();
  float s = 0.f;
#pragma unroll
  for (int i = 0; i < 16; i++) { v[i] = __expf(v[i] - mx); s += v[i]; }
#pragma unroll
  for (int o = 32; o > 0; o >>= 1) s += __shfl_xor(s, o);
  if ((t & 63) == 0) red[w] = s;
  __syncthreads();
  s = red[0] + red[1] + red[2] + red[3];
  float inv = 1.0f / s;
#pragma unroll
  for (int i = 0; i < 16; i++) p[t + i * 256] = f2b(v[i] * inv);
}

// O[row] = LayerNorm(X[row] + R[row] (+eb); g, b). Row length 512. 1 row/wave.
template <typename TX, typename TR, bool EB, typename TO>
__global__ __launch_bounds__(256)
void add_ln(const TX* __restrict__ X, const TR* __restrict__ Rr,
            const float* __restrict__ eb,
            const float* __restrict__ g, const float* __restrict__ b,
            TO* __restrict__ O) {
  const int row = blockIdx.x * 4 + (threadIdx.x >> 6);
  const int lane = threadIdx.x & 63;
  const size_t base = (size_t)row * 512 + lane * 8;
  float z[8];
  float s1 = 0.f, s2 = 0.f;
#pragma unroll
  for (int i = 0; i < 8; i++) {
    int c = lane * 8 + i;
    z[i] = to_f(X[base + i]) + to_f(Rr[base + i]) + (EB ? eb[c] : 0.0f);
    s1 += z[i]; s2 += z[i] * z[i];
  }
#pragma unroll
  for (int o = 32; o > 0; o >>= 1) { s1 += __shfl_xor(s1, o); s2 += __shfl_xor(s2, o); }
  const float mu = s1 * (1.0f / 512.0f);
  const float var = s2 * (1.0f / 512.0f) - mu * mu;
  const float rstd = rsqrtf(var + 1e-5f);
#pragma unroll
  for (int i = 0; i < 8; i++) {
    int c = lane * 8 + i;
    float vv = (z[i] - mu) * rstd * g[c] + b[c];
    if (sizeof(TO) == 2) ((u16*)O)[base + i] = f2b(vv);
    else ((float*)O)[base + i] = vv;
  }
}

__global__ __launch_bounds__(256)
void concat3(const float* __restrict__ a, const float* __restrict__ b,
             const float* __restrict__ c, float* __restrict__ o) {
  int i = threadIdx.x + blockIdx.x * 256;
  if (i < 512) o[i] = a[i];
  else if (i < 1024) o[i] = b[i - 512];
  else if (i < 1536) o[i] = c[i - 1024];
}

extern "C" void kernel_launch(void* const* d_in, const int* in_sizes, int n_in,
                              void* d_out, int out_size, void* d_ws, size_t ws_size,
                              hipStream_t stream) {
  const float* x   = (const float*)d_in[0];
  const float* Wq  = (const float*)d_in[1];
  const float* bq  = (const float*)d_in[2];
  const float* Wk  = (const float*)d_in[3];
  const float* bk  = (const float*)d_in[4];
  const float* Wv  = (const float*)d_in[5];
  const float* bv  = (const float*)d_in[6];
  const float* g1  = (const float*)d_in[7];
  const float* b1  = (const float*)d_in[8];
  const float* g2  = (const float*)d_in[9];
  const float* b2  = (const float*)d_in[10];
  const float* W1  = (const float*)d_in[11];
  const float* bf1 = (const float*)d_in[12];
  const float* W2  = (const float*)d_in[13];
  const float* bf2 = (const float*)d_in[14];
  float* out = (float*)d_out;

  char* ws = (char*)d_ws;
  const size_t MB = 1048576;
  u16*   QKV   = (u16*)(ws + 0);          // [16384,1536] bf16, 48 MB
  u16*   Vt    = (u16*)(ws + 48 * MB);    // [4,512,4096] bf16, 16 MB
  u16*   sc    = (u16*)(ws + 64 * MB);    // [2,4096,4096] bf16, 64 MB (aliased by h later)
  u16*   h     = sc;                      // [16384,2048] bf16, 64 MB
  float* attf  = (float*)(ws + 128 * MB); // [16384,512] fp32, 32 MB (aliased by ffnf later)
  float* ffnf  = attf;
  u16*   x1    = (u16*)(ws + 160 * MB);   // [16384,512] bf16, 16 MB
  u16*   wqkvt = (u16*)(ws + 176 * MB);   // [1536,512] bf16
  u16*   w1t   = wqkvt + 1536 * 512;      // [2048,512] bf16
  u16*   w2t   = w1t + 2048 * 512;        // [512,2048] bf16
  float* bqkv  = (float*)(w2t + 512 * 2048); // [1536] fp32

  dim3 tb(32, 32);
  // Weight prep (fp32 -> bf16, NT form)
  transpose_b<float><<<dim3(16, 16, 1), tb, 0, stream>>>(Wq, wqkvt,             512, 512, 512, 0, 0);
  transpose_b<float><<<dim3(16, 16, 1), tb, 0, stream>>>(Wk, wqkvt + 512 * 512, 512, 512, 512, 0, 0);
  transpose_b<float><<<dim3(16, 16, 1), tb, 0, stream>>>(Wv, wqkvt + 1024 * 512,512, 512, 512, 0, 0);
  transpose_b<float><<<dim3(64, 16, 1), tb, 0, stream>>>(W1, w1t, 512, 2048, 2048, 0, 0);
  transpose_b<float><<<dim3(16, 64, 1), tb, 0, stream>>>(W2, w2t, 2048, 512, 512, 0, 0);
  concat3<<<6, 256, 0, stream>>>(bq, bk, bv, bqkv);

  // Fused QKV projection: [16384,512] x [512,1536] -> QKV [16384,1536]
  gemm_nt<false, true, false><<<dim3(12, 128, 1), 256, 0, stream>>>(
      x, wqkvt, bqkv, QKV, 1536, 512, 1, 512, 512, 1536, 0, 0, 0, 1.0f);

  // V^T per batch: V = QKV cols [1024,1536), per-batch [4096,512] -> Vt [512,4096]
  transpose_b<u16><<<dim3(16, 128, 4), tb, 0, stream>>>(
      QKV + 1024, Vt, 4096, 512, 1536, 4096L * 1536, 512L * 4096);

  // attention accumulator zero (split-K atomics)
  hipMemsetAsync(attf, 0, 32 * MB, stream);

  const float scl = 0.044194173824159216f;  // 1/sqrt(512)
  for (int b2i = 0; b2i < 4; b2i += 2) {
    const u16* Qp = QKV + (long)b2i * 4096 * 1536;        // Q cols [0,512)
    const u16* Kp = QKV + (long)b2i * 4096 * 1536 + 512;  // K cols [512,1024)
    // scores = scale * Q K^T : [2 batches, 4096, 4096]
    gemm_nt<false, false, false><<<dim3(32, 32, 2), 256, 0, stream>>>(
        Qp, Kp, nullptr, sc, 4096, 512, 1,
        1536, 1536, 4096, 4096L * 1536, 4096L * 1536, 4096L * 4096, scl);
    softmax_inplace<<<8192, 256, 0, stream>>>(sc);
    // att += P V : split-K=4 over K=4096, fp32 atomics
    gemm_nt<false, false, true><<<dim3(4, 32, 2 * 4), 256, 0, stream>>>(
        sc, Vt + (long)b2i * 512 * 4096, nullptr, attf + (long)b2i * 4096 * 512,
        512, 4096, 4, 4096, 4096, 512, 4096L * 4096, 512L * 4096, 4096L * 512, 1.0f);
  }

  // x1 = LN(x + att)
  add_ln<float, float, false, u16><<<4096, 256, 0, stream>>>(x, attf, nullptr, g1, b1, x1);
  // h = relu(x1 W1 + bf1): [16384,2048]
  gemm_nt<true, false, false><<<dim3(16, 128, 1), 256, 0, stream>>>(
      x1, w1t, bf1, h, 2048, 512, 1, 512, 512, 2048, 0, 0, 0, 1.0f);
  // ffnf = h W2 (split-K=2, fp32 atomics; bias folded into add_ln)
  hipMemsetAsync(ffnf, 0, 32 * MB, stream);
  gemm_nt<false, false, true><<<dim3(4, 128, 2), 256, 0, stream>>>(
      h, w2t, nullptr, ffnf, 512, 2048, 2, 2048, 2048, 512, 0, 0, 0, 1.0f);
  // out = LN(x1 + ffnf + bf2) -> fp32
  add_ln<u16, float, true, float><<<4096, 256, 0, stream>>>(x1, ffnf, bf2, g2, b2, out);
}

// Round 4
// 609.741 us; speedup vs baseline: 1.4177x; 1.2569x over previous
//
#include <hip/hip_runtime.h>
#include <hip/hip_bf16.h>

typedef unsigned short u16;
typedef short bf16x8 __attribute__((ext_vector_type(8)));
typedef float f32x4 __attribute__((ext_vector_type(4)));

__device__ __forceinline__ float b2f(u16 u) {
  union { float f; unsigned int i; } v; v.i = ((unsigned int)u) << 16; return v.f;
}
__device__ __forceinline__ u16 f2b(float f) {
  union { float f; unsigned int i; } v; v.f = f;
  unsigned int r = v.i + 0x7fffu + ((v.i >> 16) & 1u);
  return (u16)(r >> 16);
}
__device__ __forceinline__ u16 to_b(float v) { return f2b(v); }
__device__ __forceinline__ u16 to_b(u16 v) { return v; }
__device__ __forceinline__ float to_f(float v) { return v; }
__device__ __forceinline__ float to_f(u16 v) { return b2f(v); }

// async 16B global -> LDS (dest = uniform lds base + lane*16)
__device__ __forceinline__ void gl_lds16(const u16* g, u16* l) {
  __builtin_amdgcn_global_load_lds(
      (const __attribute__((address_space(1))) unsigned int*)g,
      (__attribute__((address_space(3))) unsigned int*)l, 16, 0, 0);
}

// C[M,N] = A[M,K]*Bt[N,K]^T (+bias) (*scale) (ReLU / fp32-atomic split-K).
// All bf16 in; LDS tiles 128x64 unpadded, XOR-swizzled (chunk c stored at c^(row&7)),
// staged via global_load_lds width-16. blockIdx.z = batch*nsplit+split.
// M%128==0, N%128==0, (K/nsplit)%64==0.
template <bool RELU, bool ATOMIC>
__global__ __launch_bounds__(256)
void gemm_nt(const u16* __restrict__ A, const u16* __restrict__ Bt,
             const float* __restrict__ bias, void* __restrict__ Cv,
             int N, int K, int nsplit, int lda, int ldb, int ldc,
             long sA, long sB, long sC, float scale) {
  __shared__ __align__(16) u16 As[128 * 64];
  __shared__ __align__(16) u16 Bs[128 * 64];
  const int z = blockIdx.z;
  const int batch = z / nsplit, split = z - batch * nsplit;
  const int Ks = K / nsplit;
  const u16* Ab = A + (long)batch * sA + (long)split * Ks;
  const u16* Bb = Bt + (long)batch * sB + (long)split * Ks;
  const int m0 = blockIdx.y * 128, n0 = blockIdx.x * 128;
  const int t = threadIdx.x, w = t >> 6, lane = t & 63;
  const int wm = (w >> 1) * 64, wn = (w & 1) * 64;
  const int lr = lane & 15, q = lane >> 4;

  // staging map: chunk n = w*256 + i*64 + lane; row=n>>3, phys=n&7,
  // logical chunk c = phys ^ (row&7); source col = c*8 elements.
  int srow[4], scol[4];
#pragma unroll
  for (int i = 0; i < 4; i++) {
    int n = w * 256 + i * 64 + lane;
    srow[i] = n >> 3;
    scol[i] = (((n & 7) ^ ((n >> 3) & 7)) * 8);
  }

  f32x4 acc[4][4];
#pragma unroll
  for (int i = 0; i < 4; i++)
#pragma unroll
    for (int j = 0; j < 4; j++) acc[i][j] = (f32x4){0.f, 0.f, 0.f, 0.f};

  for (int k0 = 0; k0 < Ks; k0 += 64) {
#pragma unroll
    for (int i = 0; i < 4; i++) {
      u16* ldst = &As[(w * 256 + i * 64) * 8];  // wave-uniform
      gl_lds16(Ab + (long)(m0 + srow[i]) * lda + k0 + scol[i], ldst);
    }
#pragma unroll
    for (int i = 0; i < 4; i++) {
      u16* ldst = &Bs[(w * 256 + i * 64) * 8];
      gl_lds16(Bb + (long)(n0 + srow[i]) * ldb + k0 + scol[i], ldst);
    }
    __syncthreads();
#pragma unroll
    for (int kk = 0; kk < 2; kk++) {
      bf16x8 af[4], bfr[4];
#pragma unroll
      for (int i = 0; i < 4; i++) {
        int row = wm + i * 16 + lr;
        int phys = (kk * 4 + q) ^ (row & 7);
        af[i] = *(const bf16x8*)&As[row * 64 + phys * 8];
      }
#pragma unroll
      for (int j = 0; j < 4; j++) {
        int row = wn + j * 16 + lr;
        int phys = (kk * 4 + q) ^ (row & 7);
        bfr[j] = *(const bf16x8*)&Bs[row * 64 + phys * 8];
      }
#pragma unroll
      for (int i = 0; i < 4; i++)
#pragma unroll
        for (int j = 0; j < 4; j++)
          acc[i][j] = __builtin_amdgcn_mfma_f32_16x16x32_bf16(af[i], bfr[j], acc[i][j], 0, 0, 0);
    }
    __syncthreads();
  }

#pragma unroll
  for (int j = 0; j < 4; j++) {
    int cg = n0 + wn + j * 16 + lr;           // D col = lane&15
    float bb = (!ATOMIC && bias) ? bias[cg] : 0.0f;
#pragma unroll
    for (int i = 0; i < 4; i++) {
      int rbase = m0 + wm + i * 16 + q * 4;   // D row = quad*4 + reg
#pragma unroll
      for (int r = 0; r < 4; r++) {
        float vv = acc[i][j][r] * scale;
        if (ATOMIC) {
          atomicAdd((float*)Cv + (long)batch * sC + (long)(rbase + r) * ldc + cg, vv);
        } else {
          vv += bb;
          if (RELU) vv = fmaxf(vv, 0.0f);
          ((u16*)Cv)[(long)batch * sC + (long)(rbase + r) * ldc + cg] = f2b(vv);
        }
      }
    }
  }
}

// dst[z*dbs + c*R + r] = to_bf16(src[z*sbs + r*src_ld + c]). R%32==0, C%32==0.
template <typename TS>
__global__ __launch_bounds__(1024)
void transpose_b(const TS* __restrict__ src, u16* __restrict__ dst,
                 int R, int Cc, int src_ld, long sbs, long dbs) {
  __shared__ u16 tile[32][33];
  int r = blockIdx.y * 32 + threadIdx.y;
  int c = blockIdx.x * 32 + threadIdx.x;
  tile[threadIdx.y][threadIdx.x] = to_b(src[(long)blockIdx.z * sbs + (long)r * src_ld + c]);
  __syncthreads();
  int rr = blockIdx.x * 32 + threadIdx.y;
  int cc = blockIdx.y * 32 + threadIdx.x;
  dst[(long)blockIdx.z * dbs + (long)rr * R + cc] = tile[threadIdx.x][threadIdx.y];
}

__global__ __launch_bounds__(256)
void f32_to_bf16(const float* __restrict__ s, u16* __restrict__ d) {
  long i = ((long)blockIdx.x * 256 + threadIdx.x) * 8;
  float4 a0 = *(const float4*)(s + i);
  float4 a1 = *(const float4*)(s + i + 4);
  u16 tmp[8] = {f2b(a0.x), f2b(a0.y), f2b(a0.z), f2b(a0.w),
                f2b(a1.x), f2b(a1.y), f2b(a1.z), f2b(a1.w)};
  *(uint4*)(d + i) = *(uint4*)tmp;
}

// In-place row softmax over 4096 bf16 logits; one block per row.
__global__ __launch_bounds__(256)
void softmax_inplace(u16* __restrict__ S) {
  const int row = blockIdx.x;
  u16* p = S + (size_t)row * 4096;
  const int t = threadIdx.x;
  float v[16];
  float mx = -1e30f;
#pragma unroll
  for (int i = 0; i < 16; i++) { v[i] = b2f(p[t + i * 256]); mx = fmaxf(mx, v[i]); }
#pragma unroll
  for (int o = 32; o > 0; o >>= 1) mx = fmaxf(mx, __shfl_xor(mx, o));
  __shared__ float red[4];
  int w = t >> 6;
  if ((t & 63) == 0) red[w] = mx;
  __syncthreads();
  mx = fmaxf(fmaxf(red[0], red[1]), fmaxf(red[2], red[3]));
  __syncthreads();
  float s = 0.f;
#pragma unroll
  for (int i = 0; i < 16; i++) { v[i] = __expf(v[i] - mx); s += v[i]; }
#pragma unroll
  for (int o = 32; o > 0; o >>= 1) s += __shfl_xor(s, o);
  if ((t & 63) == 0) red[w] = s;
  __syncthreads();
  s = red[0] + red[1] + red[2] + red[3];
  float inv = 1.0f / s;
#pragma unroll
  for (int i = 0; i < 16; i++) p[t + i * 256] = f2b(v[i] * inv);
}

// O[row] = LayerNorm(X[row] + R[row] (+eb); g, b). Row length 512. 1 row/wave.
template <typename TX, typename TR, bool EB, typename TO>
__global__ __launch_bounds__(256)
void add_ln(const TX* __restrict__ X, const TR* __restrict__ Rr,
            const float* __restrict__ eb,
            const float* __restrict__ g, const float* __restrict__ b,
            TO* __restrict__ O) {
  const int row = blockIdx.x * 4 + (threadIdx.x >> 6);
  const int lane = threadIdx.x & 63;
  const size_t base = (size_t)row * 512 + lane * 8;
  float z[8];
  float s1 = 0.f, s2 = 0.f;
#pragma unroll
  for (int i = 0; i < 8; i++) {
    int c = lane * 8 + i;
    z[i] = to_f(X[base + i]) + to_f(Rr[base + i]) + (EB ? eb[c] : 0.0f);
    s1 += z[i]; s2 += z[i] * z[i];
  }
#pragma unroll
  for (int o = 32; o > 0; o >>= 1) { s1 += __shfl_xor(s1, o); s2 += __shfl_xor(s2, o); }
  const float mu = s1 * (1.0f / 512.0f);
  const float var = s2 * (1.0f / 512.0f) - mu * mu;
  const float rstd = rsqrtf(var + 1e-5f);
#pragma unroll
  for (int i = 0; i < 8; i++) {
    int c = lane * 8 + i;
    float vv = (z[i] - mu) * rstd * g[c] + b[c];
    if (sizeof(TO) == 2) ((u16*)O)[base + i] = f2b(vv);
    else ((float*)O)[base + i] = vv;
  }
}

__global__ __launch_bounds__(256)
void concat3(const float* __restrict__ a, const float* __restrict__ b,
             const float* __restrict__ c, float* __restrict__ o) {
  int i = threadIdx.x + blockIdx.x * 256;
  if (i < 512) o[i] = a[i];
  else if (i < 1024) o[i] = b[i - 512];
  else if (i < 1536) o[i] = c[i - 1024];
}

extern "C" void kernel_launch(void* const* d_in, const int* in_sizes, int n_in,
                              void* d_out, int out_size, void* d_ws, size_t ws_size,
                              hipStream_t stream) {
  const float* x   = (const float*)d_in[0];
  const float* Wq  = (const float*)d_in[1];
  const float* bq  = (const float*)d_in[2];
  const float* Wk  = (const float*)d_in[3];
  const float* bk  = (const float*)d_in[4];
  const float* Wv  = (const float*)d_in[5];
  const float* bv  = (const float*)d_in[6];
  const float* g1  = (const float*)d_in[7];
  const float* b1  = (const float*)d_in[8];
  const float* g2  = (const float*)d_in[9];
  const float* b2  = (const float*)d_in[10];
  const float* W1  = (const float*)d_in[11];
  const float* bf1 = (const float*)d_in[12];
  const float* W2  = (const float*)d_in[13];
  const float* bf2 = (const float*)d_in[14];
  float* out = (float*)d_out;

  char* ws = (char*)d_ws;
  const size_t MB = 1048576;
  u16*   QKV   = (u16*)(ws + 0);          // [16384,1536] bf16, 48 MB
  u16*   Vt    = (u16*)(ws + 48 * MB);    // [4,512,4096] bf16, 16 MB
  u16*   sc    = (u16*)(ws + 64 * MB);    // [2,4096,4096] bf16, 64 MB (h aliases)
  u16*   h     = sc;                      // [16384,2048] bf16, 64 MB
  float* attf  = (float*)(ws + 128 * MB); // [16384,512] fp32, 32 MB (ffnf aliases)
  float* ffnf  = attf;
  u16*   xb    = (u16*)(ws + 128 * MB);   // bf16(x), 16 MB — dead before attf memset
  u16*   x1    = (u16*)(ws + 160 * MB);   // [16384,512] bf16, 16 MB
  u16*   wqkvt = (u16*)(ws + 176 * MB);   // [1536,512] bf16
  u16*   w1t   = wqkvt + 1536 * 512;      // [2048,512] bf16
  u16*   w2t   = w1t + 2048 * 512;        // [512,2048] bf16
  float* bqkv  = (float*)(w2t + 512 * 2048); // [1536] fp32

  dim3 tb(32, 32);
  // Input / weight prep (fp32 -> bf16, NT form)
  f32_to_bf16<<<4096, 256, 0, stream>>>(x, xb);
  transpose_b<float><<<dim3(16, 16, 1), tb, 0, stream>>>(Wq, wqkvt,              512, 512, 512, 0, 0);
  transpose_b<float><<<dim3(16, 16, 1), tb, 0, stream>>>(Wk, wqkvt + 512 * 512,  512, 512, 512, 0, 0);
  transpose_b<float><<<dim3(16, 16, 1), tb, 0, stream>>>(Wv, wqkvt + 1024 * 512, 512, 512, 512, 0, 0);
  transpose_b<float><<<dim3(64, 16, 1), tb, 0, stream>>>(W1, w1t, 512, 2048, 2048, 0, 0);
  transpose_b<float><<<dim3(16, 64, 1), tb, 0, stream>>>(W2, w2t, 2048, 512, 512, 0, 0);
  concat3<<<6, 256, 0, stream>>>(bq, bk, bv, bqkv);

  // Fused QKV projection: [16384,512] x [512,1536] -> QKV
  gemm_nt<false, false><<<dim3(12, 128, 1), 256, 0, stream>>>(
      xb, wqkvt, bqkv, QKV, 1536, 512, 1, 512, 512, 1536, 0, 0, 0, 1.0f);

  // V^T per batch: V = QKV cols [1024,1536) -> Vt [512,4096]
  transpose_b<u16><<<dim3(16, 128, 4), tb, 0, stream>>>(
      QKV + 1024, Vt, 4096, 512, 1536, 4096L * 1536, 512L * 4096);

  // attention accumulator zero (split-K atomics); xb dead from here
  hipMemsetAsync(attf, 0, 32 * MB, stream);

  const float scl = 0.044194173824159216f;  // 1/sqrt(512)
  for (int b2i = 0; b2i < 4; b2i += 2) {
    const u16* Qp = QKV + (long)b2i * 4096 * 1536;
    const u16* Kp = Qp + 512;
    // scores = scale * Q K^T : [2, 4096, 4096]
    gemm_nt<false, false><<<dim3(32, 32, 2), 256, 0, stream>>>(
        Qp, Kp, nullptr, sc, 4096, 512, 1,
        1536, 1536, 4096, 4096L * 1536, 4096L * 1536, 4096L * 4096, scl);
    softmax_inplace<<<8192, 256, 0, stream>>>(sc);
    // att += P V : split-K=2 over K=4096, fp32 atomics
    gemm_nt<false, true><<<dim3(4, 32, 4), 256, 0, stream>>>(
        sc, Vt + (long)b2i * 512 * 4096, nullptr, attf + (long)b2i * 4096 * 512,
        512, 4096, 2, 4096, 4096, 512, 4096L * 4096, 512L * 4096, 4096L * 512, 1.0f);
  }

  // x1 = LN(x + att)
  add_ln<float, float, false, u16><<<4096, 256, 0, stream>>>(x, attf, nullptr, g1, b1, x1);
  // h = relu(x1 W1 + bf1)
  gemm_nt<true, false><<<dim3(16, 128, 1), 256, 0, stream>>>(
      x1, w1t, bf1, h, 2048, 512, 1, 512, 512, 2048, 0, 0, 0, 1.0f);
  // ffnf = h W2 (split-K=2, fp32 atomics; bias folded into add_ln)
  hipMemsetAsync(ffnf, 0, 32 * MB, stream);
  gemm_nt<false, true><<<dim3(4, 128, 2), 256, 0, stream>>>(
      h, w2t, nullptr, ffnf, 512, 2048, 2, 2048, 2048, 512, 0, 0, 0, 1.0f);
  // out = LN(x1 + ffnf + bf2) -> fp32
  add_ln<u16, float, true, float><<<4096, 256, 0, stream>>>(x1, ffnf, bf2, g2, b2, out);
}